// Round 1
// baseline (404.629 us; speedup 1.0000x reference)
//
#include <hip/hip_runtime.h>
#include <stdint.h>

#define GLOBAL_AS __attribute__((address_space(1)))
#define LDS_AS __attribute__((address_space(3)))

typedef float f32x4 __attribute__((ext_vector_type(4)));
typedef short bf16x8 __attribute__((ext_vector_type(8)));

static __device__ __forceinline__ unsigned short f2b(float f) {
  union { float f; unsigned u; } v; v.f = f;
  return (unsigned short)((v.u + 0x7FFFu + ((v.u >> 16) & 1u)) >> 16);
}

static __device__ __forceinline__ void async16(const void* g, void* l) {
  __builtin_amdgcn_global_load_lds((const GLOBAL_AS unsigned int*)g,
                                   (LDS_AS unsigned int*)l, 16, 0, 0);
}

// ---------------- fused prep: cast_x | rope table | 4x transpose-cast ----------------
__global__ void prep_kernel(const float* __restrict__ x,
                            const float* __restrict__ Wq, const float* __restrict__ Wk,
                            const float* __restrict__ Wv, const float* __restrict__ Wo,
                            unsigned short* __restrict__ xb,
                            unsigned short* __restrict__ WcatT, unsigned short* __restrict__ WoT,
                            float* __restrict__ cosT, float* __restrict__ sinT) {
  __shared__ float tile[32][33];
  const int bid = blockIdx.x;
  const int tid = threadIdx.x;
  if (bid < 16384) {
    const int i = bid * 256 + tid;
    float4 v = ((const float4*)x)[i];
    ushort4 o;
    o.x = f2b(v.x); o.y = f2b(v.y); o.z = f2b(v.z); o.w = f2b(v.w);
    ((ushort4*)xb)[i] = o;
  } else if (bid < 16384 + 512) {
    const int idx = (bid - 16384) * 256 + tid;
    const int s = idx >> 5, j = idx & 31;
    float freq = expf(-((float)(2 * j) * (1.0f / 64.0f)) * 9.210340371976184f);
    float ang = (float)s * freq;
    float sn, cs;
    sincosf(ang, &sn, &cs);
    cosT[idx] = cs;
    sinT[idx] = sn;
  } else {
    const int t = bid - 16896;
    const int mat = t >> 10;
    const int r = t & 1023;
    const int k0 = (r & 31) * 32, n0 = (r >> 5) * 32;
    const float* W = (mat == 0) ? Wq : (mat == 1) ? Wk : (mat == 2) ? Wv : Wo;
    unsigned short* WT = (mat < 3) ? (WcatT + (size_t)mat * 1024 * 1024) : WoT;
    const int tx = tid & 31, ty = tid >> 5;
    #pragma unroll
    for (int i = 0; i < 4; i++)
      tile[ty + i * 8][tx] = W[(size_t)(k0 + ty + i * 8) * 1024 + n0 + tx];
    __syncthreads();
    #pragma unroll
    for (int i = 0; i < 4; i++)
      WT[(size_t)(n0 + ty + i * 8) * 1024 + k0 + tx] = f2b(tile[tx][ty + i * 8]);
  }
}

// ---------------- fused QKV GEMM: BM=256 BN=128 BK=64, triple-buffer, counted vmcnt ----------------
// 512 thr / 8 waves (2M x 4N), per-wave 128x64 out = acc[8][2] (64 VGPR).
// LDS 3*(32K A + 16K B) = 144KB -> 1 block/CU, 2 waves/SIMD.
// Pipeline: compute tile t | stage tile t+2 into buf (t+2)%3 | vmcnt(6) (tile t+1 landed,
// t+2's 6 loads stay in flight across the barrier) -> never drain to 0 in steady state (T3+T4).
__global__ __launch_bounds__(512, 2)
void gemm_qkv_kernel(const unsigned short* __restrict__ xb,
                     const unsigned short* __restrict__ WT,
                     const float* __restrict__ cosT,
                     const float* __restrict__ sinT,
                     unsigned short* __restrict__ Qd,
                     unsigned short* __restrict__ KTd,
                     unsigned short* __restrict__ VTd) {
  __shared__ char sA[3][32768];
  __shared__ char sB[3][16384];
  const int tid = threadIdx.x;
  const int lane = tid & 63;
  const int wave = tid >> 6;
  const int lrow = lane & 15;
  const int quad = lane >> 4;
  const int wm = wave >> 2;
  const int wn = wave & 3;

  // XCD-aware swizzle: 1536 blocks = 8 XCDs x 192; within a chunk consecutive x share the
  // B-panel (same n-tile for 64 consecutive m-tiles) -> B hits per-XCD L2.
  const int flat = blockIdx.x;
  const int x = (flat & 7) * 192 + (flat >> 3);
  const int m0 = (x & 63) * 256;
  const int n0 = (x >> 6) * 128;

  const f32x4 zf = {0.f, 0.f, 0.f, 0.f};
  f32x4 acc[8][2];
  #pragma unroll
  for (int i = 0; i < 8; i++)
    #pragma unroll
    for (int j = 0; j < 2; j++) acc[i][j] = zf;

  // stage one K-tile (A: 4 loads, B: 2 loads per thread), source-side chunk swizzle,
  // linear LDS destination (global_load_lds constraint).
  auto stage = [&](int t, int bi) {
    const int kt = t * 64;
    #pragma unroll
    for (int l = 0; l < 4; ++l) {
      const int slot = l * 512 + tid;
      const int row = slot >> 3;
      const int ch = (slot & 7) ^ (row & 7);
      async16(xb + (size_t)(m0 + row) * 1024 + kt + ch * 8, &sA[bi][slot * 16]);
    }
    #pragma unroll
    for (int l = 0; l < 2; ++l) {
      const int slot = l * 512 + tid;
      const int row = slot >> 3;
      const int ch = (slot & 7) ^ (row & 7);
      async16(WT + (size_t)(n0 + row) * 1024 + kt + ch * 8, &sB[bi][slot * 16]);
    }
  };

  // prologue: tiles 0,1 in flight; wait tile 0 (leave tile 1's 6 loads outstanding)
  stage(0, 0);
  stage(1, 1);
  asm volatile("s_waitcnt vmcnt(6)" ::: "memory");
  __builtin_amdgcn_s_barrier();
  __builtin_amdgcn_sched_barrier(0);

  int cur = 0;
  #pragma unroll 1
  for (int t = 0; t < 16; ++t) {
    if (t < 14) {
      int nb = cur + 2; if (nb >= 3) nb -= 3;
      stage(t + 2, nb);   // buf nb's readers (tile t-1) finished before tile t began: race-free
    }
    const char* bA = sA[cur];
    const char* bB = sB[cur];
    #pragma unroll
    for (int kk = 0; kk < 2; ++kk) {
      const int kc = kk * 4 + quad;
      bf16x8 af[8], bfr[2];
      #pragma unroll
      for (int nt = 0; nt < 2; ++nt) {
        const int row = wn * 32 + nt * 16 + lrow;
        bfr[nt] = *(const bf16x8*)&bB[row * 128 + ((kc ^ (row & 7)) << 4)];
      }
      #pragma unroll
      for (int mt = 0; mt < 8; ++mt) {
        const int row = wm * 128 + mt * 16 + lrow;
        af[mt] = *(const bf16x8*)&bA[row * 128 + ((kc ^ (row & 7)) << 4)];
      }
      __builtin_amdgcn_s_setprio(1);
      #pragma unroll
      for (int mt = 0; mt < 8; ++mt)
        #pragma unroll
        for (int nt = 0; nt < 2; ++nt)
          acc[mt][nt] = __builtin_amdgcn_mfma_f32_16x16x32_bf16(af[mt], bfr[nt], acc[mt][nt], 0, 0, 0);
      __builtin_amdgcn_s_setprio(0);
    }
    if (t < 15) {
      if (t < 14) { asm volatile("s_waitcnt vmcnt(6)" ::: "memory"); }
      else        { asm volatile("s_waitcnt vmcnt(0)" ::: "memory"); }
      __builtin_amdgcn_s_barrier();
      __builtin_amdgcn_sched_barrier(0);
    }
    cur = (cur == 2) ? 0 : cur + 1;
  }

  const int b = m0 >> 12;
  const int sec = n0 >> 10;         // 0=Q 1=K 2=V
  const int s0 = (m0 & 4095) + wm * 128;
  const int c0 = (n0 & 1023) + wn * 32;

  if (sec == 2) {
    #pragma unroll
    for (int mt = 0; mt < 8; mt++) {
      const int sB4 = s0 + mt * 16 + quad * 4;
      #pragma unroll
      for (int nt = 0; nt < 2; nt++) {
        const int c = c0 + nt * 16 + lrow;
        const int h = c >> 6, e = c & 63;
        ushort4 pk;
        pk.x = f2b(acc[mt][nt][0]); pk.y = f2b(acc[mt][nt][1]);
        pk.z = f2b(acc[mt][nt][2]); pk.w = f2b(acc[mt][nt][3]);
        *(ushort4*)&VTd[((size_t)(b * 16 + h) * 64 + e) * 4096 + sB4] = pk;
      }
    }
  } else {
    #pragma unroll
    for (int mt = 0; mt < 8; mt++) {
      const int sB4 = s0 + mt * 16 + quad * 4;
      #pragma unroll
      for (int nt = 0; nt < 2; nt++) {
        const int c = c0 + nt * 16 + lrow;
        const int j = (c & 63) >> 1;
        float ov[4];
        #pragma unroll
        for (int r = 0; r < 4; r++) {
          const float v = acc[mt][nt][r];
          const float p = __shfl_xor(v, 1, 64);
          const int s = sB4 + r;
          const float cs = cosT[s * 32 + j];
          const float sn = sinT[s * 32 + j];
          const float tt = (lane & 1) ? p * sn : -p * sn;
          ov[r] = fmaxf(fmaf(v, cs, tt), 0.0f);
        }
        if (sec == 0) {
          const int grow = m0 + wm * 128 + mt * 16 + quad * 4;
          #pragma unroll
          for (int r = 0; r < 4; r++)
            Qd[(size_t)(grow + r) * 1024 + c] = f2b(ov[r]);
        } else {
          const int h = c >> 6, d = c & 63;
          ushort4 pk;
          pk.x = f2b(ov[0]); pk.y = f2b(ov[1]); pk.z = f2b(ov[2]); pk.w = f2b(ov[3]);
          *(ushort4*)&KTd[((size_t)(b * 16 + h) * 64 + d) * 4096 + sB4] = pk;
        }
      }
    }
  }
}

// ---------------- vk = V_pad^T @ K  (per b,h; K-split partials) ----------------
__global__ __launch_bounds__(256)
void vk_partial_kernel(const unsigned short* __restrict__ KTd,
                       const unsigned short* __restrict__ VTd,
                       float* __restrict__ vkp) {
  __shared__ char sV[4096];
  __shared__ char sK[4096];
  const int tid = threadIdx.x;
  const int lane = tid & 63;
  const int wave = tid >> 6;
  const int lrow = lane & 15;
  const int quad = lane >> 4;
  const int bh = blockIdx.x;
  const int kb = blockIdx.y;
  const int s00 = kb * 512;

  const f32x4 zf = {0.f, 0.f, 0.f, 0.f};
  f32x4 acc[5];
  #pragma unroll
  for (int i = 0; i < 5; i++) acc[i] = zf;

  bf16x8 af4;
  const short oneb = (short)0x3F80;
  #pragma unroll
  for (int j = 0; j < 8; j++) af4[j] = (lrow == 0) ? oneb : (short)0;

  const int srow = tid >> 2;
  const int gcol = ((tid & 3) ^ (srow & 3)) * 8;

  for (int kt = 0; kt < 512; kt += 32) {
    __syncthreads();
    async16(VTd + ((size_t)bh * 64 + srow) * 4096 + s00 + kt + gcol, &sV[tid * 16]);
    async16(KTd + ((size_t)bh * 64 + srow) * 4096 + s00 + kt + gcol, &sK[tid * 16]);
    __syncthreads();
    const int rowK = wave * 16 + lrow;
    bf16x8 bfrag = *(const bf16x8*)&sK[rowK * 64 + ((quad ^ (rowK & 3)) << 4)];
    #pragma unroll
    for (int mt = 0; mt < 4; mt++) {
      const int rowV = mt * 16 + lrow;
      bf16x8 af = *(const bf16x8*)&sV[rowV * 64 + ((quad ^ (rowV & 3)) << 4)];
      acc[mt] = __builtin_amdgcn_mfma_f32_16x16x32_bf16(af, bfrag, acc[mt], 0, 0, 0);
    }
    acc[4] = __builtin_amdgcn_mfma_f32_16x16x32_bf16(af4, bfrag, acc[4], 0, 0, 0);
  }

  #pragma unroll
  for (int mt = 0; mt < 5; mt++) {
    #pragma unroll
    for (int r = 0; r < 4; r++) {
      const int e = mt * 16 + quad * 4 + r;
      const int d = wave * 16 + lrow;
      vkp[((size_t)(bh * 8 + kb) * 80 + e) * 64 + d] = acc[mt][r];
    }
  }
}

__global__ void vk_reduce_kernel(const float* __restrict__ vkp, unsigned short* __restrict__ vkb) {
  int idx = blockIdx.x * 256 + threadIdx.x;
  if (idx >= 64 * 80 * 64) return;
  int bh = idx / 5120, r = idx % 5120;
  float s = 0.f;
  #pragma unroll
  for (int kb = 0; kb < 8; kb++) s += vkp[(size_t)(bh * 8 + kb) * 5120 + r];
  vkb[idx] = f2b(s);
}

// ---------------- num + divide -> attn ----------------
__global__ __launch_bounds__(256)
void attn_kernel(const unsigned short* __restrict__ Qd,
                 const unsigned short* __restrict__ vkb,
                 unsigned short* __restrict__ attn) {
  __shared__ char sQ[32768];
  __shared__ char sVK[10240];
  const int tid = threadIdx.x;
  const int lane = tid & 63;
  const int wave = tid >> 6;
  const int lrow = lane & 15;
  const int quad = lane >> 4;
  const int bh = blockIdx.y, b = bh >> 4, h = bh & 15;
  const int l0 = b * 4096 + blockIdx.x * 256;

  const int c4 = tid & 7;
  #pragma unroll
  for (int r = 0; r < 8; r++) {
    const int o = r * 4096 + tid * 16;
    const int row = o >> 7;
    const int g4 = c4 ^ (row & 7);
    async16(Qd + (size_t)(l0 + row) * 1024 + h * 64 + g4 * 8, &sQ[o]);
  }
  {
    int row = tid >> 3;
    int g4 = c4 ^ (row & 7);
    async16(vkb + (size_t)bh * 5120 + row * 64 + g4 * 8, &sVK[tid * 16]);
    row += 32; g4 = c4 ^ (row & 7);
    async16(vkb + (size_t)bh * 5120 + row * 64 + g4 * 8, &sVK[4096 + tid * 16]);
    if (tid < 128) {
      row = 64 + (tid >> 3); g4 = c4 ^ (row & 7);
      async16(vkb + (size_t)bh * 5120 + row * 64 + g4 * 8, &sVK[8192 + tid * 16]);
    }
  }
  __syncthreads();

  const f32x4 zf = {0.f, 0.f, 0.f, 0.f};
  f32x4 acc[4][5];
  #pragma unroll
  for (int i = 0; i < 4; i++)
    #pragma unroll
    for (int j = 0; j < 5; j++) acc[i][j] = zf;

  #pragma unroll
  for (int kk = 0; kk < 2; kk++) {
    const int kc = kk * 4 + quad;
    bf16x8 af[4], bfr[5];
    #pragma unroll
    for (int mt = 0; mt < 4; mt++) {
      const int row = wave * 64 + mt * 16 + lrow;
      af[mt] = *(const bf16x8*)&sQ[row * 128 + ((kc ^ (row & 7)) << 4)];
    }
    #pragma unroll
    for (int nt = 0; nt < 5; nt++) {
      const int row = nt * 16 + lrow;
      bfr[nt] = *(const bf16x8*)&sVK[row * 128 + ((kc ^ (row & 7)) << 4)];
    }
    #pragma unroll
    for (int mt = 0; mt < 4; mt++)
      #pragma unroll
      for (int nt = 0; nt < 5; nt++)
        acc[mt][nt] = __builtin_amdgcn_mfma_f32_16x16x32_bf16(af[mt], bfr[nt], acc[mt][nt], 0, 0, 0);
  }

  #pragma unroll
  for (int mt = 0; mt < 4; mt++) {
    #pragma unroll
    for (int r = 0; r < 4; r++) {
      const float den = __shfl(acc[mt][4][r], lane & 48, 64);
      const float inv = 1.0f / (den + 1e-6f);
      const int l = l0 + wave * 64 + mt * 16 + quad * 4 + r;
      #pragma unroll
      for (int nt = 0; nt < 4; nt++)
        attn[(size_t)l * 1024 + h * 64 + nt * 16 + lrow] = f2b(acc[mt][nt][r] * inv);
    }
  }
}

// ---------------- out = attn @ Wo : same triple-buffer pipeline ----------------
__global__ __launch_bounds__(512, 2)
void gemm_out_kernel(const unsigned short* __restrict__ A,
                     const unsigned short* __restrict__ BT,
                     float* __restrict__ C) {
  __shared__ char sA[3][32768];
  __shared__ char sB[3][16384];
  const int tid = threadIdx.x;
  const int lane = tid & 63;
  const int wave = tid >> 6;
  const int lrow = lane & 15;
  const int quad = lane >> 4;
  const int wm = wave >> 2;
  const int wn = wave & 3;

  // 512 blocks = 8 XCDs x 64
  const int flat = blockIdx.x;
  const int x = (flat & 7) * 64 + (flat >> 3);
  const int m0 = (x & 63) * 256;
  const int n0 = (x >> 6) * 128;

  const f32x4 zf = {0.f, 0.f, 0.f, 0.f};
  f32x4 acc[8][2];
  #pragma unroll
  for (int i = 0; i < 8; i++)
    #pragma unroll
    for (int j = 0; j < 2; j++) acc[i][j] = zf;

  auto stage = [&](int t, int bi) {
    const int kt = t * 64;
    #pragma unroll
    for (int l = 0; l < 4; ++l) {
      const int slot = l * 512 + tid;
      const int row = slot >> 3;
      const int ch = (slot & 7) ^ (row & 7);
      async16(A + (size_t)(m0 + row) * 1024 + kt + ch * 8, &sA[bi][slot * 16]);
    }
    #pragma unroll
    for (int l = 0; l < 2; ++l) {
      const int slot = l * 512 + tid;
      const int row = slot >> 3;
      const int ch = (slot & 7) ^ (row & 7);
      async16(BT + (size_t)(n0 + row) * 1024 + kt + ch * 8, &sB[bi][slot * 16]);
    }
  };

  stage(0, 0);
  stage(1, 1);
  asm volatile("s_waitcnt vmcnt(6)" ::: "memory");
  __builtin_amdgcn_s_barrier();
  __builtin_amdgcn_sched_barrier(0);

  int cur = 0;
  #pragma unroll 1
  for (int t = 0; t < 16; ++t) {
    if (t < 14) {
      int nb = cur + 2; if (nb >= 3) nb -= 3;
      stage(t + 2, nb);
    }
    const char* bA = sA[cur];
    const char* bB = sB[cur];
    #pragma unroll
    for (int kk = 0; kk < 2; ++kk) {
      const int kc = kk * 4 + quad;
      bf16x8 af[8], bfr[2];
      #pragma unroll
      for (int nt = 0; nt < 2; ++nt) {
        const int row = wn * 32 + nt * 16 + lrow;
        bfr[nt] = *(const bf16x8*)&bB[row * 128 + ((kc ^ (row & 7)) << 4)];
      }
      #pragma unroll
      for (int mt = 0; mt < 8; ++mt) {
        const int row = wm * 128 + mt * 16 + lrow;
        af[mt] = *(const bf16x8*)&bA[row * 128 + ((kc ^ (row & 7)) << 4)];
      }
      __builtin_amdgcn_s_setprio(1);
      #pragma unroll
      for (int mt = 0; mt < 8; ++mt)
        #pragma unroll
        for (int nt = 0; nt < 2; ++nt)
          acc[mt][nt] = __builtin_amdgcn_mfma_f32_16x16x32_bf16(af[mt], bfr[nt], acc[mt][nt], 0, 0, 0);
      __builtin_amdgcn_s_setprio(0);
    }
    if (t < 15) {
      if (t < 14) { asm volatile("s_waitcnt vmcnt(6)" ::: "memory"); }
      else        { asm volatile("s_waitcnt vmcnt(0)" ::: "memory"); }
      __builtin_amdgcn_s_barrier();
      __builtin_amdgcn_sched_barrier(0);
    }
    cur = (cur == 2) ? 0 : cur + 1;
  }

  const int grow = m0 + wm * 128;
  #pragma unroll
  for (int mt = 0; mt < 8; mt++) {
    #pragma unroll
    for (int nt = 0; nt < 2; nt++) {
      const int c = n0 + wn * 32 + nt * 16 + lrow;
      #pragma unroll
      for (int r = 0; r < 4; r++)
        C[(size_t)(grow + mt * 16 + quad * 4 + r) * 1024 + c] = acc[mt][nt][r];
    }
  }
}

extern "C" void kernel_launch(void* const* d_in, const int* in_sizes, int n_in,
                              void* d_out, int out_size, void* d_ws, size_t ws_size,
                              hipStream_t stream) {
  const float* x  = (const float*)d_in[0];
  const float* Wq = (const float*)d_in[1];
  const float* Wk = (const float*)d_in[2];
  const float* Wv = (const float*)d_in[3];
  const float* Wo = (const float*)d_in[4];
  float* out = (float*)d_out;

  char* ws = (char*)d_ws;
  size_t off = 0;
  auto alloc = [&](size_t bytes) -> char* {
    char* p = ws + off;
    off += (bytes + 255) & ~(size_t)255;
    return p;
  };

  unsigned short* xb    = (unsigned short*)alloc((size_t)16384 * 1024 * 2);
  unsigned short* WcatT = (unsigned short*)alloc((size_t)3072 * 1024 * 2);
  unsigned short* WoT   = (unsigned short*)alloc((size_t)1024 * 1024 * 2);
  float* cosT           = (float*)alloc((size_t)4096 * 32 * 4);
  float* sinT           = (float*)alloc((size_t)4096 * 32 * 4);
  unsigned short* Qd    = (unsigned short*)alloc((size_t)16384 * 1024 * 2);
  unsigned short* KTd   = (unsigned short*)alloc((size_t)64 * 64 * 4096 * 2);
  unsigned short* VTd   = (unsigned short*)alloc((size_t)64 * 64 * 4096 * 2);
  float* vkp            = (float*)alloc((size_t)512 * 5120 * 4);
  unsigned short* vkb   = (unsigned short*)alloc((size_t)64 * 5120 * 2);
  unsigned short* attn  = xb; // xb dead after gemm_qkv

  prep_kernel<<<16384 + 512 + 4096, 256, 0, stream>>>(x, Wq, Wk, Wv, Wo, xb, WcatT, WoT, cosT, sinT);
  gemm_qkv_kernel<<<1536, 512, 0, stream>>>(xb, WcatT, cosT, sinT, Qd, KTd, VTd);
  vk_partial_kernel<<<dim3(64, 8), 256, 0, stream>>>(KTd, VTd, vkp);
  vk_reduce_kernel<<<1280, 256, 0, stream>>>(vkp, vkb);
  attn_kernel<<<dim3(16, 64), 256, 0, stream>>>(Qd, vkb, attn);
  gemm_out_kernel<<<512, 512, 0, stream>>>(attn, WoT, out);
}

// Round 2
// 324.017 us; speedup vs baseline: 1.2488x; 1.2488x over previous
//
#include <hip/hip_runtime.h>
#include <stdint.h>

#define GLOBAL_AS __attribute__((address_space(1)))
#define LDS_AS __attribute__((address_space(3)))

typedef float f32x4 __attribute__((ext_vector_type(4)));
typedef short bf16x8 __attribute__((ext_vector_type(8)));

static __device__ __forceinline__ unsigned short f2b(float f) {
  union { float f; unsigned u; } v; v.f = f;
  return (unsigned short)((v.u + 0x7FFFu + ((v.u >> 16) & 1u)) >> 16);
}

static __device__ __forceinline__ void async16(const void* g, void* l) {
  __builtin_amdgcn_global_load_lds((const GLOBAL_AS unsigned int*)g,
                                   (LDS_AS unsigned int*)l, 16, 0, 0);
}

#define BAR() do { __builtin_amdgcn_s_barrier(); __builtin_amdgcn_sched_barrier(0); } while (0)

// ---------------- fused prep: cast_x | rope table | 4x transpose-cast ----------------
__global__ void prep_kernel(const float* __restrict__ x,
                            const float* __restrict__ Wq, const float* __restrict__ Wk,
                            const float* __restrict__ Wv, const float* __restrict__ Wo,
                            unsigned short* __restrict__ xb,
                            unsigned short* __restrict__ WcatT, unsigned short* __restrict__ WoT,
                            float* __restrict__ cosT, float* __restrict__ sinT) {
  __shared__ float tile[32][33];
  const int bid = blockIdx.x;
  const int tid = threadIdx.x;
  if (bid < 16384) {
    const int i = bid * 256 + tid;
    float4 v = ((const float4*)x)[i];
    ushort4 o;
    o.x = f2b(v.x); o.y = f2b(v.y); o.z = f2b(v.z); o.w = f2b(v.w);
    ((ushort4*)xb)[i] = o;
  } else if (bid < 16384 + 512) {
    const int idx = (bid - 16384) * 256 + tid;
    const int s = idx >> 5, j = idx & 31;
    float freq = expf(-((float)(2 * j) * (1.0f / 64.0f)) * 9.210340371976184f);
    float ang = (float)s * freq;
    float sn, cs;
    sincosf(ang, &sn, &cs);
    cosT[idx] = cs;
    sinT[idx] = sn;
  } else {
    const int t = bid - 16896;
    const int mat = t >> 10;
    const int r = t & 1023;
    const int k0 = (r & 31) * 32, n0 = (r >> 5) * 32;
    const float* W = (mat == 0) ? Wq : (mat == 1) ? Wk : (mat == 2) ? Wv : Wo;
    unsigned short* WT = (mat < 3) ? (WcatT + (size_t)mat * 1024 * 1024) : WoT;
    const int tx = tid & 31, ty = tid >> 5;
    #pragma unroll
    for (int i = 0; i < 4; i++)
      tile[ty + i * 8][tx] = W[(size_t)(k0 + ty + i * 8) * 1024 + n0 + tx];
    __syncthreads();
    #pragma unroll
    for (int i = 0; i < 4; i++)
      WT[(size_t)(n0 + ty + i * 8) * 1024 + k0 + tx] = f2b(tile[tx][ty + i * 8]);
  }
}

// ---------------- 256x256x(K=1024) 8-phase core (m201 template, plain HIP) ----------------
// 512 thr / 8 waves (2M x 4N), wave tile 128x64, acc[8][4]. BK=64.
// LDS: 2 dbuf x {A0,A1,B0,B1} half-tiles of 128x64 bf16 (16KB each) = 128KB.
// Per K-tile 4 phases: {ds_read subtile | stage 1 half-tile | BAR | 16 MFMA | BAR}.
// Stage slots: ph1->(t+1).A0, ph2->(t+1).A1, ph3->(t+2).B0, ph4->(t+2).B1.
// One counted wait per K-tile: vmcnt(4) before the tile boundary barrier (t=14: vmcnt(0)).
// 2 barriers/phase are required: phase-p reads must drain (lgkmcnt before MFMA, then BAR)
// before any wave issues phase-p+1's stage over the same region (e.g. B0 read in ph2,
// staged over in ph3).
__device__ __forceinline__ void gemm256_core(const unsigned short* __restrict__ Ag,
                                             const unsigned short* __restrict__ Bg,
                                             int m0, int n0, char* lds, f32x4 (&acc)[8][4]) {
  const int tid = threadIdx.x;
  const int lane = tid & 63;
  const int lrow = lane & 15;
  const int quad = lane >> 4;
  const int wave = tid >> 6;
  const int wm = wave >> 2;
  const int wn = wave & 3;

  const unsigned short* Ar0 = Ag + (size_t)m0 * 1024;
  const unsigned short* Ar1 = Ag + (size_t)(m0 + 128) * 1024;
  const unsigned short* Br0 = Bg + (size_t)n0 * 1024;
  const unsigned short* Br1 = Bg + (size_t)(n0 + 128) * 1024;

  // one half-tile = 128 rows x 64 cols bf16 = 1024 slots of 16B; 2 loads/thread.
  // source-side chunk swizzle (ch ^ row&7), linear LDS dest -> conflict-free ds_read_b128.
  auto stage = [&](const unsigned short* src, char* dst) {
    #pragma unroll
    for (int l = 0; l < 2; ++l) {
      const int slot = l * 512 + tid;
      const int row = slot >> 3;
      const int ch = (slot & 7) ^ (row & 7);
      async16(src + (size_t)row * 1024 + ch * 8, dst + slot * 16);
    }
  };

  // prologue: tile0 all 4 halves, then tile1's B halves (as-if ph3/ph4 of tile -1)
  stage(Ar0, lds);
  stage(Ar1, lds + 16384);
  stage(Br0, lds + 32768);
  stage(Br1, lds + 49152);
  stage(Br0 + 64, lds + 65536 + 32768);
  stage(Br1 + 64, lds + 65536 + 49152);
  asm volatile("s_waitcnt vmcnt(4)" ::: "memory");
  BAR();

  #pragma unroll 1
  for (int t = 0; t < 16; ++t) {
    const int kt = t * 64;
    char* cur = lds + ((t & 1) << 16);
    char* nxt = lds + (((t + 1) & 1) << 16);
    const char* aB = cur + wm * 16384;                 // this wave's A half
    const char* bB = cur + 32768 + (wn >> 1) * 16384;  // this wave's B half
    const int br0 = (wn & 1) * 64;

    bf16x8 a[4][2], b01[2][2], b23[2][2];

    // -------- ph1: read a(q0, 8) + b01 (4); stage (t+1).A0 --------
    #pragma unroll
    for (int mt = 0; mt < 4; ++mt) {
      const int r = mt * 16 + lrow;
      #pragma unroll
      for (int kk = 0; kk < 2; ++kk) {
        const int kc = kk * 4 + quad;
        a[mt][kk] = *(const bf16x8*)(aB + r * 128 + ((kc ^ (r & 7)) << 4));
      }
    }
    #pragma unroll
    for (int nt = 0; nt < 2; ++nt) {
      const int r = br0 + nt * 16 + lrow;
      #pragma unroll
      for (int kk = 0; kk < 2; ++kk) {
        const int kc = kk * 4 + quad;
        b01[nt][kk] = *(const bf16x8*)(bB + r * 128 + ((kc ^ (r & 7)) << 4));
      }
    }
    if (t < 15) stage(Ar0 + kt + 64, nxt);
    BAR();
    __builtin_amdgcn_s_setprio(1);
    #pragma unroll
    for (int mt = 0; mt < 4; ++mt)
      #pragma unroll
      for (int nt = 0; nt < 2; ++nt)
        #pragma unroll
        for (int kk = 0; kk < 2; ++kk)
          acc[mt][nt] = __builtin_amdgcn_mfma_f32_16x16x32_bf16(a[mt][kk], b01[nt][kk], acc[mt][nt], 0, 0, 0);
    __builtin_amdgcn_s_setprio(0);
    BAR();

    // -------- ph2: read b23 (4); stage (t+1).A1 --------
    #pragma unroll
    for (int nt = 0; nt < 2; ++nt) {
      const int r = br0 + (nt + 2) * 16 + lrow;
      #pragma unroll
      for (int kk = 0; kk < 2; ++kk) {
        const int kc = kk * 4 + quad;
        b23[nt][kk] = *(const bf16x8*)(bB + r * 128 + ((kc ^ (r & 7)) << 4));
      }
    }
    if (t < 15) stage(Ar1 + kt + 64, nxt + 16384);
    BAR();
    __builtin_amdgcn_s_setprio(1);
    #pragma unroll
    for (int mt = 0; mt < 4; ++mt)
      #pragma unroll
      for (int nt = 0; nt < 2; ++nt)
        #pragma unroll
        for (int kk = 0; kk < 2; ++kk)
          acc[mt][nt + 2] = __builtin_amdgcn_mfma_f32_16x16x32_bf16(a[mt][kk], b23[nt][kk], acc[mt][nt + 2], 0, 0, 0);
    __builtin_amdgcn_s_setprio(0);
    BAR();

    // -------- ph3: read a(q1, 8); stage (t+2).B0 --------
    #pragma unroll
    for (int mt = 0; mt < 4; ++mt) {
      const int r = 64 + mt * 16 + lrow;
      #pragma unroll
      for (int kk = 0; kk < 2; ++kk) {
        const int kc = kk * 4 + quad;
        a[mt][kk] = *(const bf16x8*)(aB + r * 128 + ((kc ^ (r & 7)) << 4));
      }
    }
    if (t < 14) stage(Br0 + kt + 128, cur + 32768);
    BAR();
    __builtin_amdgcn_s_setprio(1);
    #pragma unroll
    for (int mt = 0; mt < 4; ++mt)
      #pragma unroll
      for (int nt = 0; nt < 2; ++nt)
        #pragma unroll
        for (int kk = 0; kk < 2; ++kk)
          acc[mt + 4][nt + 2] = __builtin_amdgcn_mfma_f32_16x16x32_bf16(a[mt][kk], b23[nt][kk], acc[mt + 4][nt + 2], 0, 0, 0);
    __builtin_amdgcn_s_setprio(0);
    BAR();

    // -------- ph4: no reads; stage (t+2).B1; counted wait --------
    if (t < 14) stage(Br1 + kt + 128, cur + 49152);
    BAR();
    __builtin_amdgcn_s_setprio(1);
    #pragma unroll
    for (int mt = 0; mt < 4; ++mt)
      #pragma unroll
      for (int nt = 0; nt < 2; ++nt)
        #pragma unroll
        for (int kk = 0; kk < 2; ++kk)
          acc[mt + 4][nt] = __builtin_amdgcn_mfma_f32_16x16x32_bf16(a[mt][kk], b01[nt][kk], acc[mt + 4][nt], 0, 0, 0);
    __builtin_amdgcn_s_setprio(0);
    if (t < 14)      { asm volatile("s_waitcnt vmcnt(4)" ::: "memory"); }
    else if (t == 14){ asm volatile("s_waitcnt vmcnt(0)" ::: "memory"); }
    BAR();
  }
}

// ---------------- fused QKV GEMM ----------------
__global__ __launch_bounds__(512, 2)
void gemm_qkv_kernel(const unsigned short* __restrict__ xb,
                     const unsigned short* __restrict__ WT,
                     const float* __restrict__ cosT,
                     const float* __restrict__ sinT,
                     unsigned short* __restrict__ Qd,
                     unsigned short* __restrict__ KTd,
                     unsigned short* __restrict__ VTd) {
  __shared__ char lds[131072];
  const int m0 = blockIdx.x * 256;
  const int n0 = blockIdx.y * 256;

  f32x4 acc[8][4];
  #pragma unroll
  for (int i = 0; i < 8; ++i)
    #pragma unroll
    for (int j = 0; j < 4; ++j) acc[i][j] = (f32x4){0.f, 0.f, 0.f, 0.f};

  gemm256_core(xb, WT, m0, n0, lds, acc);

  const int tid = threadIdx.x;
  const int lane = tid & 63;
  const int lrow = lane & 15;
  const int quad = lane >> 4;
  const int wave = tid >> 6;
  const int wm = wave >> 2;
  const int wn = wave & 3;

  const int b = m0 >> 12;
  const int sec = n0 >> 10;          // 0=Q 1=K 2=V (256-wide tile stays in one section)
  const int s0 = (m0 & 4095) + wm * 128;
  const int c0 = (n0 & 1023) + wn * 64;

  if (sec == 2) {
    #pragma unroll
    for (int i = 0; i < 8; ++i) {
      const int sB4 = s0 + i * 16 + quad * 4;
      #pragma unroll
      for (int nt = 0; nt < 4; ++nt) {
        const int c = c0 + nt * 16 + lrow;
        const int h = c >> 6, e = c & 63;
        ushort4 pk;
        pk.x = f2b(acc[i][nt][0]); pk.y = f2b(acc[i][nt][1]);
        pk.z = f2b(acc[i][nt][2]); pk.w = f2b(acc[i][nt][3]);
        *(ushort4*)&VTd[((size_t)(b * 16 + h) * 64 + e) * 4096 + sB4] = pk;
      }
    }
  } else {
    #pragma unroll
    for (int i = 0; i < 8; ++i) {
      const int sB4 = s0 + i * 16 + quad * 4;
      #pragma unroll
      for (int nt = 0; nt < 4; ++nt) {
        const int c = c0 + nt * 16 + lrow;
        const int j = (c & 63) >> 1;
        float ov[4];
        #pragma unroll
        for (int r = 0; r < 4; ++r) {
          const float v = acc[i][nt][r];
          const float p = __shfl_xor(v, 1, 64);
          const int s = sB4 + r;
          const float cs = cosT[s * 32 + j];
          const float sn = sinT[s * 32 + j];
          const float tt = (lane & 1) ? p * sn : -p * sn;
          ov[r] = fmaxf(fmaf(v, cs, tt), 0.0f);
        }
        if (sec == 0) {
          const int grow = m0 + wm * 128 + i * 16 + quad * 4;
          #pragma unroll
          for (int r = 0; r < 4; ++r)
            Qd[(size_t)(grow + r) * 1024 + c] = f2b(ov[r]);
        } else {
          const int h = c >> 6, d = c & 63;
          ushort4 pk;
          pk.x = f2b(ov[0]); pk.y = f2b(ov[1]); pk.z = f2b(ov[2]); pk.w = f2b(ov[3]);
          *(ushort4*)&KTd[((size_t)(b * 16 + h) * 64 + d) * 4096 + sB4] = pk;
        }
      }
    }
  }
}

// ---------------- vk = V_pad^T @ K  (per b,h; K-split partials) ----------------
__global__ __launch_bounds__(256)
void vk_partial_kernel(const unsigned short* __restrict__ KTd,
                       const unsigned short* __restrict__ VTd,
                       float* __restrict__ vkp) {
  __shared__ char sV[4096];
  __shared__ char sK[4096];
  const int tid = threadIdx.x;
  const int lane = tid & 63;
  const int wave = tid >> 6;
  const int lrow = lane & 15;
  const int quad = lane >> 4;
  const int bh = blockIdx.x;
  const int kb = blockIdx.y;
  const int s00 = kb * 512;

  const f32x4 zf = {0.f, 0.f, 0.f, 0.f};
  f32x4 acc[5];
  #pragma unroll
  for (int i = 0; i < 5; i++) acc[i] = zf;

  bf16x8 af4;
  const short oneb = (short)0x3F80;
  #pragma unroll
  for (int j = 0; j < 8; j++) af4[j] = (lrow == 0) ? oneb : (short)0;

  const int srow = tid >> 2;
  const int gcol = ((tid & 3) ^ (srow & 3)) * 8;

  for (int kt = 0; kt < 512; kt += 32) {
    __syncthreads();
    async16(VTd + ((size_t)bh * 64 + srow) * 4096 + s00 + kt + gcol, &sV[tid * 16]);
    async16(KTd + ((size_t)bh * 64 + srow) * 4096 + s00 + kt + gcol, &sK[tid * 16]);
    __syncthreads();
    const int rowK = wave * 16 + lrow;
    bf16x8 bfrag = *(const bf16x8*)&sK[rowK * 64 + ((quad ^ (rowK & 3)) << 4)];
    #pragma unroll
    for (int mt = 0; mt < 4; mt++) {
      const int rowV = mt * 16 + lrow;
      bf16x8 af = *(const bf16x8*)&sV[rowV * 64 + ((quad ^ (rowV & 3)) << 4)];
      acc[mt] = __builtin_amdgcn_mfma_f32_16x16x32_bf16(af, bfrag, acc[mt], 0, 0, 0);
    }
    acc[4] = __builtin_amdgcn_mfma_f32_16x16x32_bf16(af4, bfrag, acc[4], 0, 0, 0);
  }

  #pragma unroll
  for (int mt = 0; mt < 5; mt++) {
    #pragma unroll
    for (int r = 0; r < 4; r++) {
      const int e = mt * 16 + quad * 4 + r;
      const int d = wave * 16 + lrow;
      vkp[((size_t)(bh * 8 + kb) * 80 + e) * 64 + d] = acc[mt][r];
    }
  }
}

__global__ void vk_reduce_kernel(const float* __restrict__ vkp, unsigned short* __restrict__ vkb) {
  int idx = blockIdx.x * 256 + threadIdx.x;
  if (idx >= 64 * 80 * 64) return;
  int bh = idx / 5120, r = idx % 5120;
  float s = 0.f;
  #pragma unroll
  for (int kb = 0; kb < 8; kb++) s += vkp[(size_t)(bh * 8 + kb) * 5120 + r];
  vkb[idx] = f2b(s);
}

// ---------------- num + divide -> attn ----------------
__global__ __launch_bounds__(256)
void attn_kernel(const unsigned short* __restrict__ Qd,
                 const unsigned short* __restrict__ vkb,
                 unsigned short* __restrict__ attn) {
  __shared__ char sQ[32768];
  __shared__ char sVK[10240];
  const int tid = threadIdx.x;
  const int lane = tid & 63;
  const int wave = tid >> 6;
  const int lrow = lane & 15;
  const int quad = lane >> 4;
  const int bh = blockIdx.y, b = bh >> 4, h = bh & 15;
  const int l0 = b * 4096 + blockIdx.x * 256;

  const int c4 = tid & 7;
  #pragma unroll
  for (int r = 0; r < 8; r++) {
    const int o = r * 4096 + tid * 16;
    const int row = o >> 7;
    const int g4 = c4 ^ (row & 7);
    async16(Qd + (size_t)(l0 + row) * 1024 + h * 64 + g4 * 8, &sQ[o]);
  }
  {
    int row = tid >> 3;
    int g4 = c4 ^ (row & 7);
    async16(vkb + (size_t)bh * 5120 + row * 64 + g4 * 8, &sVK[tid * 16]);
    row += 32; g4 = c4 ^ (row & 7);
    async16(vkb + (size_t)bh * 5120 + row * 64 + g4 * 8, &sVK[4096 + tid * 16]);
    if (tid < 128) {
      row = 64 + (tid >> 3); g4 = c4 ^ (row & 7);
      async16(vkb + (size_t)bh * 5120 + row * 64 + g4 * 8, &sVK[8192 + tid * 16]);
    }
  }
  __syncthreads();

  const f32x4 zf = {0.f, 0.f, 0.f, 0.f};
  f32x4 acc[4][5];
  #pragma unroll
  for (int i = 0; i < 4; i++)
    #pragma unroll
    for (int j = 0; j < 5; j++) acc[i][j] = zf;

  #pragma unroll
  for (int kk = 0; kk < 2; kk++) {
    const int kc = kk * 4 + quad;
    bf16x8 af[4], bfr[5];
    #pragma unroll
    for (int mt = 0; mt < 4; mt++) {
      const int row = wave * 64 + mt * 16 + lrow;
      af[mt] = *(const bf16x8*)&sQ[row * 128 + ((kc ^ (row & 7)) << 4)];
    }
    #pragma unroll
    for (int nt = 0; nt < 5; nt++) {
      const int row = nt * 16 + lrow;
      bfr[nt] = *(const bf16x8*)&sVK[row * 128 + ((kc ^ (row & 7)) << 4)];
    }
    #pragma unroll
    for (int mt = 0; mt < 4; mt++)
      #pragma unroll
      for (int nt = 0; nt < 5; nt++)
        acc[mt][nt] = __builtin_amdgcn_mfma_f32_16x16x32_bf16(af[mt], bfr[nt], acc[mt][nt], 0, 0, 0);
  }

  #pragma unroll
  for (int mt = 0; mt < 4; mt++) {
    #pragma unroll
    for (int r = 0; r < 4; r++) {
      const float den = __shfl(acc[mt][4][r], lane & 48, 64);
      const float inv = 1.0f / (den + 1e-6f);
      const int l = l0 + wave * 64 + mt * 16 + quad * 4 + r;
      #pragma unroll
      for (int nt = 0; nt < 4; nt++)
        attn[(size_t)l * 1024 + h * 64 + nt * 16 + lrow] = f2b(acc[mt][nt][r] * inv);
    }
  }
}

// ---------------- out = attn @ Wo : same 8-phase core, f32 epilogue ----------------
__global__ __launch_bounds__(512, 2)
void gemm_out_kernel(const unsigned short* __restrict__ A,
                     const unsigned short* __restrict__ BT,
                     float* __restrict__ C) {
  __shared__ char lds[131072];
  const int m0 = blockIdx.x * 256;
  const int n0 = blockIdx.y * 256;

  f32x4 acc[8][4];
  #pragma unroll
  for (int i = 0; i < 8; ++i)
    #pragma unroll
    for (int j = 0; j < 4; ++j) acc[i][j] = (f32x4){0.f, 0.f, 0.f, 0.f};

  gemm256_core(A, BT, m0, n0, lds, acc);

  const int tid = threadIdx.x;
  const int lane = tid & 63;
  const int lrow = lane & 15;
  const int quad = lane >> 4;
  const int wave = tid >> 6;
  const int wm = wave >> 2;
  const int wn = wave & 3;

  const int grow = m0 + wm * 128;
  #pragma unroll
  for (int i = 0; i < 8; ++i) {
    #pragma unroll
    for (int nt = 0; nt < 4; ++nt) {
      const int c = n0 + wn * 64 + nt * 16 + lrow;
      #pragma unroll
      for (int r = 0; r < 4; ++r)
        C[(size_t)(grow + i * 16 + quad * 4 + r) * 1024 + c] = acc[i][nt][r];
    }
  }
}

extern "C" void kernel_launch(void* const* d_in, const int* in_sizes, int n_in,
                              void* d_out, int out_size, void* d_ws, size_t ws_size,
                              hipStream_t stream) {
  const float* x  = (const float*)d_in[0];
  const float* Wq = (const float*)d_in[1];
  const float* Wk = (const float*)d_in[2];
  const float* Wv = (const float*)d_in[3];
  const float* Wo = (const float*)d_in[4];
  float* out = (float*)d_out;

  char* ws = (char*)d_ws;
  size_t off = 0;
  auto alloc = [&](size_t bytes) -> char* {
    char* p = ws + off;
    off += (bytes + 255) & ~(size_t)255;
    return p;
  };

  unsigned short* xb    = (unsigned short*)alloc((size_t)16384 * 1024 * 2);
  unsigned short* WcatT = (unsigned short*)alloc((size_t)3072 * 1024 * 2);
  unsigned short* WoT   = (unsigned short*)alloc((size_t)1024 * 1024 * 2);
  float* cosT           = (float*)alloc((size_t)4096 * 32 * 4);
  float* sinT           = (float*)alloc((size_t)4096 * 32 * 4);
  unsigned short* Qd    = (unsigned short*)alloc((size_t)16384 * 1024 * 2);
  unsigned short* KTd   = (unsigned short*)alloc((size_t)64 * 64 * 4096 * 2);
  unsigned short* VTd   = (unsigned short*)alloc((size_t)64 * 64 * 4096 * 2);
  float* vkp            = (float*)alloc((size_t)512 * 5120 * 4);
  unsigned short* vkb   = (unsigned short*)alloc((size_t)64 * 5120 * 2);
  unsigned short* attn  = xb; // xb dead after gemm_qkv

  prep_kernel<<<16384 + 512 + 4096, 256, 0, stream>>>(x, Wq, Wk, Wv, Wo, xb, WcatT, WoT, cosT, sinT);
  gemm_qkv_kernel<<<dim3(64, 12), 512, 0, stream>>>(xb, WcatT, cosT, sinT, Qd, KTd, VTd);
  vk_partial_kernel<<<dim3(64, 8), 256, 0, stream>>>(KTd, VTd, vkp);
  vk_reduce_kernel<<<1280, 256, 0, stream>>>(vkp, vkb);
  attn_kernel<<<dim3(16, 64), 256, 0, stream>>>(Qd, vkb, attn);
  gemm_out_kernel<<<dim3(64, 4), 512, 0, stream>>>(attn, WoT, out);
}